// Round 11
// baseline (97.838 us; speedup 1.0000x reference)
//
#include <hip/hip_runtime.h>
#include <hip/hip_bf16.h>
#include <math.h>

#define S_LEN 2048
#define C_DIM 512
#define NH 16
#define HD 32
#define PLANE_U (NH * S_LEN * HD)   // 1,048,576 ushorts = 2MB per plane

typedef __attribute__((ext_vector_type(8))) short bf16x8;
typedef __attribute__((ext_vector_type(8))) unsigned short u16x8;
typedef __attribute__((ext_vector_type(4))) float f32x4;
typedef __attribute__((ext_vector_type(4))) unsigned int u32x4;

__device__ __forceinline__ unsigned short f2b(float f) {
    unsigned int x = __float_as_uint(f);
    unsigned int r = (x + 0x7FFFu + ((x >> 16) & 1u)) >> 16;   // RNE
    return (unsigned short)r;
}

// pack 2 floats -> 2 bf16 in one dword via v_cvt_pk_bf16_f32 (RNE); a = low
__device__ __forceinline__ unsigned int pk_bf16(float a, float b) {
    float2 f; f.x = a; f.y = b;
    __hip_bfloat162 t = __float22bfloat162_rn(f);
    return *reinterpret_cast<unsigned int*>(&t);
}

// ---------------- projection: complex GEMM via bf16 MFMA ------------------
// z<2 (q,k): hi/lo split (12 mfma/tile-chunk), D = W·X^T -> [h][s][d]; the Q
//            plane is PRE-SCALED by 1/sqrt(32) (|c*s| = c*|s|, c>0).
//            hi = truncation (v_perm pair-pack), lo = RNE cvt_pk of residual.
// z==2 (v):  hi-only RNE (4 mfma/tile-chunk, err ~0.006), D = X·W^T -> V^T
//            plane [h][d][s] with key axis permuted within each 32-group
//            (pos u*16+g*4+r -> col g*8+u*4+r) for attn's swapped PV.
#define PROW 40   // padded LDS row stride in ushorts (80B, 16B-aligned)

__global__ __launch_bounds__(256)
void proj_mfma(const float* __restrict__ Q, const float* __restrict__ V,
               const float* __restrict__ K,
               const float* __restrict__ Wq, const float* __restrict__ bq,
               const float* __restrict__ Wk, const float* __restrict__ bk,
               const float* __restrict__ Wv, const float* __restrict__ bv,
               unsigned short* __restrict__ ws)
{
    const int z = blockIdx.z;
    const float *X, *W, *b;
    if (z == 0)      { X = Q; W = Wq; b = bq; }
    else if (z == 1) { X = K; W = Wk; b = bk; }
    else             { X = V; W = Wv; b = bv; }
    const bool full = (z < 2);

    const int s0 = blockIdx.x * 64;
    const int o0 = blockIdx.y * 64;

    const float2 *Asrc, *Bsrc; int arow0, brow0;
    if (full) { Asrc = (const float2*)W; arow0 = o0; Bsrc = (const float2*)X; brow0 = s0; }
    else      { Asrc = (const float2*)X; arow0 = s0; Bsrc = (const float2*)W; brow0 = o0; }

    __shared__ __align__(16) unsigned short LArh[64*PROW], LArl[64*PROW];
    __shared__ __align__(16) unsigned short LAih[64*PROW], LAil[64*PROW];
    __shared__ __align__(16) unsigned short LBrh[64*PROW], LBrl[64*PROW];
    __shared__ __align__(16) unsigned short LBih[64*PROW], LBil[64*PROW];

    const int t    = threadIdx.x;
    const int wave = t >> 6;
    const int lr   = t & 15;
    const int g    = (t & 63) >> 4;
    const int srow = t >> 2;        // staging row 0..63
    const int sk8  = (t & 3) * 8;   // staging k chunk (8 complex)

    const f32x4 zf = {0.f,0.f,0.f,0.f};
    f32x4 accR[4], accI[4];
    #pragma unroll
    for (int i = 0; i < 4; ++i) { accR[i] = zf; accI[i] = zf; }

    for (int k0 = 0; k0 < C_DIM; k0 += 32) {
        __syncthreads();
        // ---- stage A then B tile ----
        #pragma unroll
        for (int ab = 0; ab < 2; ++ab) {
            const float2* src = ab ? Bsrc : Asrc;
            const int     r0  = ab ? brow0 : arow0;
            const float4* s4 = (const float4*)(src + (size_t)(r0 + srow)*C_DIM + k0 + sk8);
            float4 f0 = s4[0], f1 = s4[1], f2v = s4[2], f3 = s4[3];
            float re[8] = {f0.x,f0.z,f1.x,f1.z,f2v.x,f2v.z,f3.x,f3.z};
            float im[8] = {f0.y,f0.w,f1.y,f1.w,f2v.y,f2v.w,f3.y,f3.w};
            u32x4 rh, ih, rl, il;
            if (full) {
                #pragma unroll
                for (int p2 = 0; p2 < 4; ++p2) {
                    float r0f = re[2*p2], r1f = re[2*p2+1];
                    float i0f = im[2*p2], i1f = im[2*p2+1];
                    unsigned int br0 = __float_as_uint(r0f), br1 = __float_as_uint(r1f);
                    unsigned int bi0 = __float_as_uint(i0f), bi1 = __float_as_uint(i1f);
                    rh[p2] = __builtin_amdgcn_perm(br1, br0, 0x07060302u);  // [hi16(r1):hi16(r0)]
                    ih[p2] = __builtin_amdgcn_perm(bi1, bi0, 0x07060302u);
                    rl[p2] = pk_bf16(r0f - __uint_as_float(br0 & 0xFFFF0000u),
                                     r1f - __uint_as_float(br1 & 0xFFFF0000u));
                    il[p2] = pk_bf16(i0f - __uint_as_float(bi0 & 0xFFFF0000u),
                                     i1f - __uint_as_float(bi1 & 0xFFFF0000u));
                }
            } else {
                #pragma unroll
                for (int p2 = 0; p2 < 4; ++p2) {
                    rh[p2] = pk_bf16(re[2*p2], re[2*p2+1]);
                    ih[p2] = pk_bf16(im[2*p2], im[2*p2+1]);
                }
            }
            int wb = srow*PROW + sk8;
            if (ab == 0) {
                *(u32x4*)&LArh[wb] = rh; *(u32x4*)&LAih[wb] = ih;
                if (full) { *(u32x4*)&LArl[wb] = rl; *(u32x4*)&LAil[wb] = il; }
            } else {
                *(u32x4*)&LBrh[wb] = rh; *(u32x4*)&LBih[wb] = ih;
                if (full) { *(u32x4*)&LBrl[wb] = rl; *(u32x4*)&LBil[wb] = il; }
            }
        }
        __syncthreads();

        // ---- A fragments (wave's 16 rows) ----
        const int ab = (wave*16 + lr)*PROW + g*8;
        bf16x8 aRH = *(const bf16x8*)&LArh[ab];
        bf16x8 aIH = *(const bf16x8*)&LAih[ab];
        bf16x8 aIHn;
        #pragma unroll
        for (int j = 0; j < 8; ++j) aIHn[j] = aIH[j] ^ (short)0x8000;

        if (full) {
            bf16x8 aRL = *(const bf16x8*)&LArl[ab];
            bf16x8 aIL = *(const bf16x8*)&LAil[ab];
            bf16x8 aILn;
            #pragma unroll
            for (int j = 0; j < 8; ++j) aILn[j] = aIL[j] ^ (short)0x8000;

            #pragma unroll
            for (int tile = 0; tile < 4; ++tile) {
                const int bb = (tile*16 + lr)*PROW + g*8;
                bf16x8 bRH = *(const bf16x8*)&LBrh[bb];
                bf16x8 bRL = *(const bf16x8*)&LBrl[bb];
                bf16x8 bIH = *(const bf16x8*)&LBih[bb];
                bf16x8 bIL = *(const bf16x8*)&LBil[bb];
                accR[tile] = __builtin_amdgcn_mfma_f32_16x16x32_bf16(aRH,  bRH, accR[tile], 0,0,0);
                accR[tile] = __builtin_amdgcn_mfma_f32_16x16x32_bf16(aRL,  bRH, accR[tile], 0,0,0);
                accR[tile] = __builtin_amdgcn_mfma_f32_16x16x32_bf16(aRH,  bRL, accR[tile], 0,0,0);
                accR[tile] = __builtin_amdgcn_mfma_f32_16x16x32_bf16(aIHn, bIH, accR[tile], 0,0,0);
                accR[tile] = __builtin_amdgcn_mfma_f32_16x16x32_bf16(aILn, bIH, accR[tile], 0,0,0);
                accR[tile] = __builtin_amdgcn_mfma_f32_16x16x32_bf16(aIHn, bIL, accR[tile], 0,0,0);
                accI[tile] = __builtin_amdgcn_mfma_f32_16x16x32_bf16(aRH,  bIH, accI[tile], 0,0,0);
                accI[tile] = __builtin_amdgcn_mfma_f32_16x16x32_bf16(aRL,  bIH, accI[tile], 0,0,0);
                accI[tile] = __builtin_amdgcn_mfma_f32_16x16x32_bf16(aRH,  bIL, accI[tile], 0,0,0);
                accI[tile] = __builtin_amdgcn_mfma_f32_16x16x32_bf16(aIH,  bRH, accI[tile], 0,0,0);
                accI[tile] = __builtin_amdgcn_mfma_f32_16x16x32_bf16(aIL,  bRH, accI[tile], 0,0,0);
                accI[tile] = __builtin_amdgcn_mfma_f32_16x16x32_bf16(aIH,  bRL, accI[tile], 0,0,0);
            }
        } else {
            #pragma unroll
            for (int tile = 0; tile < 4; ++tile) {
                const int bb = (tile*16 + lr)*PROW + g*8;
                bf16x8 bRH = *(const bf16x8*)&LBrh[bb];
                bf16x8 bIH = *(const bf16x8*)&LBih[bb];
                accR[tile] = __builtin_amdgcn_mfma_f32_16x16x32_bf16(aRH,  bRH, accR[tile], 0,0,0);
                accR[tile] = __builtin_amdgcn_mfma_f32_16x16x32_bf16(aIHn, bIH, accR[tile], 0,0,0);
                accI[tile] = __builtin_amdgcn_mfma_f32_16x16x32_bf16(aRH,  bIH, accI[tile], 0,0,0);
                accI[tile] = __builtin_amdgcn_mfma_f32_16x16x32_bf16(aIH,  bRH, accI[tile], 0,0,0);
            }
        }
    }

    // ---- epilogue ----
    const float2* b2 = (const float2*)b;
    if (full) {
        // Q plane pre-scaled by 1/sqrt(32) (fold softmax scale into scores)
        const float osc = (z == 0) ? 0.17677669529663687f : 1.0f;
        unsigned short* pr = ws + (z == 0 ? 0 : 2) * (size_t)PLANE_U;
        unsigned short* pi = pr + PLANE_U;
        const int obase = o0 + wave*16 + g*4;
        const int h = obase >> 5, d0 = obase & 31;
        float bR[4], bI[4];
        #pragma unroll
        for (int r = 0; r < 4; ++r) { float2 bb = b2[obase + r]; bR[r] = bb.x; bI[r] = bb.y; }
        #pragma unroll
        for (int tile = 0; tile < 4; ++tile) {
            int s = s0 + tile*16 + lr;
            size_t idx = ((size_t)h*S_LEN + s)*HD + d0;
            uint2 pkR, pkI;
            pkR.x = pk_bf16((accR[tile][0]+bR[0])*osc, (accR[tile][1]+bR[1])*osc);
            pkR.y = pk_bf16((accR[tile][2]+bR[2])*osc, (accR[tile][3]+bR[3])*osc);
            pkI.x = pk_bf16((accI[tile][0]+bI[0])*osc, (accI[tile][1]+bI[1])*osc);
            pkI.y = pk_bf16((accI[tile][2]+bI[2])*osc, (accI[tile][3]+bI[3])*osc);
            *(uint2*)&pr[idx] = pkR;
            *(uint2*)&pi[idx] = pkI;
        }
    } else {
        unsigned short* tr = ws + 4 * (size_t)PLANE_U;
        unsigned short* ti = tr + PLANE_U;
        // key s = s0 + wave*16 + g*4 + r  ->  permuted column
        // c = s0 + (wave>>1)*32 + g*8 + (wave&1)*4 + r  (bijective in [0,64))
        const int cbase = s0 + (wave >> 1)*32 + g*8 + (wave & 1)*4;
        #pragma unroll
        for (int tile = 0; tile < 4; ++tile) {
            int o = o0 + tile*16 + lr;
            int h = o >> 5, d = o & 31;
            float2 bb = b2[o];
            size_t idx = ((size_t)h*HD + d)*S_LEN + cbase;
            uint2 pkR, pkI;
            pkR.x = pk_bf16(accR[tile][0]+bb.x, accR[tile][1]+bb.x);
            pkR.y = pk_bf16(accR[tile][2]+bb.x, accR[tile][3]+bb.x);
            pkI.x = pk_bf16(accI[tile][0]+bb.y, accI[tile][1]+bb.y);
            pkI.y = pk_bf16(accI[tile][2]+bb.y, accI[tile][3]+bb.y);
            *(uint2*)&tr[idx] = pkR;
            *(uint2*)&ti[idx] = pkI;
        }
    }
}

// ---------------- MFMA flash attention, split-K + 2 q-strips/wave --------
// Swapped QK^T: S = mfma(K,Q) -> lane (g,lr) holds S[key=u*16+g*4+r][q=lr].
// Swapped PV:   O^T = mfma(V^T, P), V^T c-permuted -> P stays in registers,
// packed via v_cvt_pk_bf16_f32 (2 floats/inst). The conj negation is applied
// to the TRANSIENT K fragment (-Ki, 4 xor/u, shared by both strips) instead
// of holding negated Q fragments (-8 VGPR -> +1 wave/SIMD at the reg cap).
// NO LDS in the main loop. Q plane pre-scaled by 1/sqrt(32). Combine is
// two-stage into a [4][16][33]-padded region (conflict-free; l in pad slot).
// min-waves stays 4 (8 caps at 32 VGPR and spills, round 4).
#define RROW 33                      // padded row stride in float2

__global__ __launch_bounds__(512, 4)
void attn_mfma(const unsigned short* __restrict__ ws, float* __restrict__ out)
{
    const int bid   = blockIdx.x;       // 64 pairs x 16 heads
    const int h     = bid & (NH - 1);   // bid%8 = head%8 -> per-XCD KV locality
    const int pair  = bid >> 4;         // 0..63
    const int wave  = threadIdx.x >> 6; // 0..7 -> k-range owner
    const int lr    = threadIdx.x & 15;
    const int g     = (threadIdx.x & 63) >> 4;

    const unsigned short* qr  = ws + 0*(size_t)PLANE_U + (size_t)h*S_LEN*HD;
    const unsigned short* qi  = ws + 1*(size_t)PLANE_U + (size_t)h*S_LEN*HD;
    const unsigned short* kr  = ws + 2*(size_t)PLANE_U + (size_t)h*S_LEN*HD;
    const unsigned short* ki  = ws + 3*(size_t)PLANE_U + (size_t)h*S_LEN*HD;
    const unsigned short* vtr = ws + 4*(size_t)PLANE_U + (size_t)h*HD*S_LEN;
    const unsigned short* vti = ws + 5*(size_t)PLANE_U + (size_t)h*HD*S_LEN;

    const int qA = pair * 32;           // strip A rows qA..qA+15
    const int qB = qA + 16;             // strip B rows qB..qB+15

    // Q fragments (B-operand of QK): lane supplies Q[q=lr][k=g*8+j]
    bf16x8 bQrA = *(const bf16x8*)&qr[(size_t)(qA + lr)*HD + g*8];
    bf16x8 bQiA = *(const bf16x8*)&qi[(size_t)(qA + lr)*HD + g*8];
    bf16x8 bQrB = *(const bf16x8*)&qr[(size_t)(qB + lr)*HD + g*8];
    bf16x8 bQiB = *(const bf16x8*)&qi[(size_t)(qB + lr)*HD + g*8];

    // LDS only for the end-of-kernel two-stage combine: [4][16][33] float2
    __shared__ __align__(16) float2 red[4*16*RROW];

    const f32x4 zf = {0.f, 0.f, 0.f, 0.f};
    f32x4 accA[2][2], accB[2][2];       // [d-tile][0=real,1=imag]
    #pragma unroll
    for (int dt = 0; dt < 2; ++dt) {
        accA[dt][0] = zf; accA[dt][1] = zf;
        accB[dt][0] = zf; accB[dt][1] = zf;
    }
    float lA = 0.f, lB = 0.f;           // denom partials for q=lr

    const int kbeg = wave * 256;
    #pragma unroll 2
    for (int k0 = kbeg; k0 < kbeg + 256; k0 += 32) {
        // ---- one 32-key group: 16 QK mfma (2 strips) -> softmax -> 8 PV --
        bf16x8 bPA, bPB;                // P packed as PV B-fragments
        unsigned int* pA32 = (unsigned int*)&bPA;
        unsigned int* pB32 = (unsigned int*)&bPB;
        #pragma unroll
        for (int u = 0; u < 2; ++u) {
            const size_t krow = (size_t)(k0 + u*16 + lr)*HD + g*8;
            bf16x8 aKr = *(const bf16x8*)&kr[krow];
            bf16x8 aKi = *(const bf16x8*)&ki[krow];
            bf16x8 aKin;                // -Ki (transient, shared by strips)
            #pragma unroll
            for (int j = 0; j < 4; ++j)
                ((unsigned int*)&aKin)[j] = ((const unsigned int*)&aKi)[j] ^ 0x80008000u;
            // strip A: re = kr.qr + ki.qi ; im = kr.qi + (-ki).qr
            {
                f32x4 sR = __builtin_amdgcn_mfma_f32_16x16x32_bf16(aKi,  bQiA, zf, 0, 0, 0);
                sR       = __builtin_amdgcn_mfma_f32_16x16x32_bf16(aKr,  bQrA, sR, 0, 0, 0);
                f32x4 sI = __builtin_amdgcn_mfma_f32_16x16x32_bf16(aKin, bQrA, zf, 0, 0, 0);
                sI       = __builtin_amdgcn_mfma_f32_16x16x32_bf16(aKr,  bQiA, sI, 0, 0, 0);
                float v0 = __expf(__builtin_amdgcn_sqrtf(fmaf(sR[0], sR[0], sI[0]*sI[0])));
                float v1 = __expf(__builtin_amdgcn_sqrtf(fmaf(sR[1], sR[1], sI[1]*sI[1])));
                float v2 = __expf(__builtin_amdgcn_sqrtf(fmaf(sR[2], sR[2], sI[2]*sI[2])));
                float v3 = __expf(__builtin_amdgcn_sqrtf(fmaf(sR[3], sR[3], sI[3]*sI[3])));
                lA += (v0 + v1) + (v2 + v3);
                pA32[u*2 + 0] = pk_bf16(v0, v1);
                pA32[u*2 + 1] = pk_bf16(v2, v3);
            }
            // strip B
            {
                f32x4 sR = __builtin_amdgcn_mfma_f32_16x16x32_bf16(aKi,  bQiB, zf, 0, 0, 0);
                sR       = __builtin_amdgcn_mfma_f32_16x16x32_bf16(aKr,  bQrB, sR, 0, 0, 0);
                f32x4 sI = __builtin_amdgcn_mfma_f32_16x16x32_bf16(aKin, bQrB, zf, 0, 0, 0);
                sI       = __builtin_amdgcn_mfma_f32_16x16x32_bf16(aKr,  bQiB, sI, 0, 0, 0);
                float v0 = __expf(__builtin_amdgcn_sqrtf(fmaf(sR[0], sR[0], sI[0]*sI[0])));
                float v1 = __expf(__builtin_amdgcn_sqrtf(fmaf(sR[1], sR[1], sI[1]*sI[1])));
                float v2 = __expf(__builtin_amdgcn_sqrtf(fmaf(sR[2], sR[2], sI[2]*sI[2])));
                float v3 = __expf(__builtin_amdgcn_sqrtf(fmaf(sR[3], sR[3], sI[3]*sI[3])));
                lB += (v0 + v1) + (v2 + v3);
                pB32[u*2 + 0] = pk_bf16(v0, v1);
                pB32[u*2 + 1] = pk_bf16(v2, v3);
            }
        }
        // ---- PV: A = V^T (c-permuted plane, 16B loads), B = P in-register
        #pragma unroll
        for (int dt = 0; dt < 2; ++dt) {
            const size_t vrow = (size_t)(dt*16 + lr)*S_LEN + k0 + g*8;
            bf16x8 aVr = *(const bf16x8*)&vtr[vrow];
            bf16x8 aVi = *(const bf16x8*)&vti[vrow];
            accA[dt][0] = __builtin_amdgcn_mfma_f32_16x16x32_bf16(aVr, bPA, accA[dt][0], 0, 0, 0);
            accA[dt][1] = __builtin_amdgcn_mfma_f32_16x16x32_bf16(aVi, bPA, accA[dt][1], 0, 0, 0);
            accB[dt][0] = __builtin_amdgcn_mfma_f32_16x16x32_bf16(aVr, bPB, accB[dt][0], 0, 0, 0);
            accB[dt][1] = __builtin_amdgcn_mfma_f32_16x16x32_bf16(aVi, bPB, accB[dt][1], 0, 0, 0);
        }
    }

    // ---- wave l-reduction: q=lr slices live at lanes lr, lr+16, lr+32, lr+48
    lA += __shfl_xor(lA, 16); lA += __shfl_xor(lA, 32);
    lB += __shfl_xor(lB, 16); lB += __shfl_xor(lB, 32);

    // ---- two-stage block combine ----
    float2* o2 = (float2*)out;
    #pragma unroll
    for (int strip = 0; strip < 2; ++strip) {
        const f32x4 (*acc)[2] = strip ? accB : accA;
        const float  lval     = strip ? lB : lA;
        const int    qbase    = strip ? qB : qA;
        __syncthreads();
        if (wave < 4) {
            // PV D layout: lane (g,lr) holds O[q=lr][d = dt*16 + g*4 + r]
            #pragma unroll
            for (int dt = 0; dt < 2; ++dt)
                #pragma unroll
                for (int r = 0; r < 4; ++r)
                    red[(wave*16 + lr)*RROW + dt*16 + g*4 + r] =
                        make_float2(acc[dt][0][r], acc[dt][1][r]);
            if (g == 0) red[(wave*16 + lr)*RROW + 32].x = lval;
        }
        __syncthreads();
        if (wave >= 4) {
            const int w = wave - 4;
            #pragma unroll
            for (int dt = 0; dt < 2; ++dt)
                #pragma unroll
                for (int r = 0; r < 4; ++r) {
                    int idx = (w*16 + lr)*RROW + dt*16 + g*4 + r;
                    float2 v = red[idx];
                    v.x += acc[dt][0][r]; v.y += acc[dt][1][r];
                    red[idx] = v;
                }
            if (g == 0) red[(w*16 + lr)*RROW + 32].x += lval;
        }
        __syncthreads();
        // thread i sums 4 partials for output element (q = i>>5, d = i&31)
        const int i = threadIdx.x;
        const int q = i >> 5, d = i & 31;
        float sr = 0.f, si = 0.f, sl = 0.f;
        #pragma unroll
        for (int w = 0; w < 4; ++w) {
            float2 v = red[(w*16 + q)*RROW + d];
            sr += v.x; si += v.y;
            sl += red[(w*16 + q)*RROW + 32].x;
        }
        float inv = 1.0f / sl;
        o2[(size_t)(qbase + q)*C_DIM + h*HD + d] = make_float2(sr*inv, si*inv);
    }
}

extern "C" void kernel_launch(void* const* d_in, const int* in_sizes, int n_in,
                              void* d_out, int out_size, void* d_ws, size_t ws_size,
                              hipStream_t stream)
{
    const float* Q  = (const float*)d_in[0];
    const float* V  = (const float*)d_in[1];
    const float* K  = (const float*)d_in[2];
    const float* Wq = (const float*)d_in[3];
    const float* bq = (const float*)d_in[4];
    const float* Wk = (const float*)d_in[5];
    const float* bk = (const float*)d_in[6];
    const float* Wv = (const float*)d_in[7];
    const float* bv = (const float*)d_in[8];
    unsigned short* ws = (unsigned short*)d_ws;   // 6 planes * 2MB = 12MB
    float* out = (float*)d_out;

    dim3 gp(S_LEN/64, C_DIM/64, 3);
    proj_mfma<<<gp, 256, 0, stream>>>(Q, V, K, Wq, bq, Wk, bk, Wv, bv, ws);

    attn_mfma<<<dim3(64*NH), 512, 0, stream>>>(ws, out);
}

// Round 12
// 94.667 us; speedup vs baseline: 1.0335x; 1.0335x over previous
//
#include <hip/hip_runtime.h>
#include <hip/hip_bf16.h>
#include <math.h>

#define S_LEN 2048
#define C_DIM 512
#define NH 16
#define HD 32
#define PLANE_U (NH * S_LEN * HD)   // 1,048,576 ushorts = 2MB per plane

typedef __attribute__((ext_vector_type(8)))  short bf16x8;
typedef __attribute__((ext_vector_type(8)))  unsigned short u16x8;
typedef __attribute__((ext_vector_type(4)))  float f32x4;
typedef __attribute__((ext_vector_type(16))) float f32x16;
typedef __attribute__((ext_vector_type(4)))  unsigned int u32x4;

// pack 2 floats -> 2 bf16 in one dword via v_cvt_pk_bf16_f32 (RNE); a = low
__device__ __forceinline__ unsigned int pk_bf16(float a, float b) {
    float2 f; f.x = a; f.y = b;
    __hip_bfloat162 t = __float22bfloat162_rn(f);
    return *reinterpret_cast<unsigned int*>(&t);
}

// ---------------- projection: complex GEMM via bf16 MFMA ------------------
// z<2 (q,k): hi/lo split (12 mfma/tile-chunk), D = W·X^T -> [h][s][d]; the Q
//            plane is PRE-SCALED by 1/sqrt(32) (|c*s| = c*|s|, c>0).
// z==2 (v):  hi-only RNE (4 mfma/tile-chunk, err ~0.006), D = X·W^T -> V^T
//            plane [h][d][s], NATURAL key order (attn reads it as the PV
//            A-operand with the standard 32x32x16 fragment layout).
#define PROW 40   // padded LDS row stride in ushorts (80B, 16B-aligned)

__global__ __launch_bounds__(256)
void proj_mfma(const float* __restrict__ Q, const float* __restrict__ V,
               const float* __restrict__ K,
               const float* __restrict__ Wq, const float* __restrict__ bq,
               const float* __restrict__ Wk, const float* __restrict__ bk,
               const float* __restrict__ Wv, const float* __restrict__ bv,
               unsigned short* __restrict__ ws)
{
    const int z = blockIdx.z;
    const float *X, *W, *b;
    if (z == 0)      { X = Q; W = Wq; b = bq; }
    else if (z == 1) { X = K; W = Wk; b = bk; }
    else             { X = V; W = Wv; b = bv; }
    const bool full = (z < 2);

    const int s0 = blockIdx.x * 64;
    const int o0 = blockIdx.y * 64;

    const float2 *Asrc, *Bsrc; int arow0, brow0;
    if (full) { Asrc = (const float2*)W; arow0 = o0; Bsrc = (const float2*)X; brow0 = s0; }
    else      { Asrc = (const float2*)X; arow0 = s0; Bsrc = (const float2*)W; brow0 = o0; }

    __shared__ __align__(16) unsigned short LArh[64*PROW], LArl[64*PROW];
    __shared__ __align__(16) unsigned short LAih[64*PROW], LAil[64*PROW];
    __shared__ __align__(16) unsigned short LBrh[64*PROW], LBrl[64*PROW];
    __shared__ __align__(16) unsigned short LBih[64*PROW], LBil[64*PROW];

    const int t    = threadIdx.x;
    const int wave = t >> 6;
    const int lr   = t & 15;
    const int g    = (t & 63) >> 4;
    const int srow = t >> 2;        // staging row 0..63
    const int sk8  = (t & 3) * 8;   // staging k chunk (8 complex)

    const f32x4 zf = {0.f,0.f,0.f,0.f};
    f32x4 accR[4], accI[4];
    #pragma unroll
    for (int i = 0; i < 4; ++i) { accR[i] = zf; accI[i] = zf; }

    for (int k0 = 0; k0 < C_DIM; k0 += 32) {
        __syncthreads();
        // ---- stage A then B tile ----
        #pragma unroll
        for (int ab = 0; ab < 2; ++ab) {
            const float2* src = ab ? Bsrc : Asrc;
            const int     r0  = ab ? brow0 : arow0;
            const float4* s4 = (const float4*)(src + (size_t)(r0 + srow)*C_DIM + k0 + sk8);
            float4 f0 = s4[0], f1 = s4[1], f2v = s4[2], f3 = s4[3];
            float re[8] = {f0.x,f0.z,f1.x,f1.z,f2v.x,f2v.z,f3.x,f3.z};
            float im[8] = {f0.y,f0.w,f1.y,f1.w,f2v.y,f2v.w,f3.y,f3.w};
            u32x4 rh, ih, rl, il;
            if (full) {
                #pragma unroll
                for (int p2 = 0; p2 < 4; ++p2) {
                    float r0f = re[2*p2], r1f = re[2*p2+1];
                    float i0f = im[2*p2], i1f = im[2*p2+1];
                    unsigned int br0 = __float_as_uint(r0f), br1 = __float_as_uint(r1f);
                    unsigned int bi0 = __float_as_uint(i0f), bi1 = __float_as_uint(i1f);
                    rh[p2] = __builtin_amdgcn_perm(br1, br0, 0x07060302u);  // [hi16(r1):hi16(r0)]
                    ih[p2] = __builtin_amdgcn_perm(bi1, bi0, 0x07060302u);
                    rl[p2] = pk_bf16(r0f - __uint_as_float(br0 & 0xFFFF0000u),
                                     r1f - __uint_as_float(br1 & 0xFFFF0000u));
                    il[p2] = pk_bf16(i0f - __uint_as_float(bi0 & 0xFFFF0000u),
                                     i1f - __uint_as_float(bi1 & 0xFFFF0000u));
                }
            } else {
                #pragma unroll
                for (int p2 = 0; p2 < 4; ++p2) {
                    rh[p2] = pk_bf16(re[2*p2], re[2*p2+1]);
                    ih[p2] = pk_bf16(im[2*p2], im[2*p2+1]);
                }
            }
            int wb = srow*PROW + sk8;
            if (ab == 0) {
                *(u32x4*)&LArh[wb] = rh; *(u32x4*)&LAih[wb] = ih;
                if (full) { *(u32x4*)&LArl[wb] = rl; *(u32x4*)&LAil[wb] = il; }
            } else {
                *(u32x4*)&LBrh[wb] = rh; *(u32x4*)&LBih[wb] = ih;
                if (full) { *(u32x4*)&LBrl[wb] = rl; *(u32x4*)&LBil[wb] = il; }
            }
        }
        __syncthreads();

        // ---- A fragments (wave's 16 rows) ----
        const int ab = (wave*16 + lr)*PROW + g*8;
        bf16x8 aRH = *(const bf16x8*)&LArh[ab];
        bf16x8 aIH = *(const bf16x8*)&LAih[ab];
        bf16x8 aIHn;
        #pragma unroll
        for (int j = 0; j < 8; ++j) aIHn[j] = aIH[j] ^ (short)0x8000;

        if (full) {
            bf16x8 aRL = *(const bf16x8*)&LArl[ab];
            bf16x8 aIL = *(const bf16x8*)&LAil[ab];
            bf16x8 aILn;
            #pragma unroll
            for (int j = 0; j < 8; ++j) aILn[j] = aIL[j] ^ (short)0x8000;

            #pragma unroll
            for (int tile = 0; tile < 4; ++tile) {
                const int bb = (tile*16 + lr)*PROW + g*8;
                bf16x8 bRH = *(const bf16x8*)&LBrh[bb];
                bf16x8 bRL = *(const bf16x8*)&LBrl[bb];
                bf16x8 bIH = *(const bf16x8*)&LBih[bb];
                bf16x8 bIL = *(const bf16x8*)&LBil[bb];
                accR[tile] = __builtin_amdgcn_mfma_f32_16x16x32_bf16(aRH,  bRH, accR[tile], 0,0,0);
                accR[tile] = __builtin_amdgcn_mfma_f32_16x16x32_bf16(aRL,  bRH, accR[tile], 0,0,0);
                accR[tile] = __builtin_amdgcn_mfma_f32_16x16x32_bf16(aRH,  bRL, accR[tile], 0,0,0);
                accR[tile] = __builtin_amdgcn_mfma_f32_16x16x32_bf16(aIHn, bIH, accR[tile], 0,0,0);
                accR[tile] = __builtin_amdgcn_mfma_f32_16x16x32_bf16(aILn, bIH, accR[tile], 0,0,0);
                accR[tile] = __builtin_amdgcn_mfma_f32_16x16x32_bf16(aIHn, bIL, accR[tile], 0,0,0);
                accI[tile] = __builtin_amdgcn_mfma_f32_16x16x32_bf16(aRH,  bIH, accI[tile], 0,0,0);
                accI[tile] = __builtin_amdgcn_mfma_f32_16x16x32_bf16(aRL,  bIH, accI[tile], 0,0,0);
                accI[tile] = __builtin_amdgcn_mfma_f32_16x16x32_bf16(aRH,  bIL, accI[tile], 0,0,0);
                accI[tile] = __builtin_amdgcn_mfma_f32_16x16x32_bf16(aIH,  bRH, accI[tile], 0,0,0);
                accI[tile] = __builtin_amdgcn_mfma_f32_16x16x32_bf16(aIL,  bRH, accI[tile], 0,0,0);
                accI[tile] = __builtin_amdgcn_mfma_f32_16x16x32_bf16(aIH,  bRL, accI[tile], 0,0,0);
            }
        } else {
            #pragma unroll
            for (int tile = 0; tile < 4; ++tile) {
                const int bb = (tile*16 + lr)*PROW + g*8;
                bf16x8 bRH = *(const bf16x8*)&LBrh[bb];
                bf16x8 bIH = *(const bf16x8*)&LBih[bb];
                accR[tile] = __builtin_amdgcn_mfma_f32_16x16x32_bf16(aRH,  bRH, accR[tile], 0,0,0);
                accR[tile] = __builtin_amdgcn_mfma_f32_16x16x32_bf16(aIHn, bIH, accR[tile], 0,0,0);
                accI[tile] = __builtin_amdgcn_mfma_f32_16x16x32_bf16(aRH,  bIH, accI[tile], 0,0,0);
                accI[tile] = __builtin_amdgcn_mfma_f32_16x16x32_bf16(aIH,  bRH, accI[tile], 0,0,0);
            }
        }
    }

    // ---- epilogue ----
    const float2* b2 = (const float2*)b;
    if (full) {
        // Q plane pre-scaled by 1/sqrt(32) (fold softmax scale into scores)
        const float osc = (z == 0) ? 0.17677669529663687f : 1.0f;
        unsigned short* pr = ws + (z == 0 ? 0 : 2) * (size_t)PLANE_U;
        unsigned short* pi = pr + PLANE_U;
        const int obase = o0 + wave*16 + g*4;
        const int h = obase >> 5, d0 = obase & 31;
        float bR[4], bI[4];
        #pragma unroll
        for (int r = 0; r < 4; ++r) { float2 bb = b2[obase + r]; bR[r] = bb.x; bI[r] = bb.y; }
        #pragma unroll
        for (int tile = 0; tile < 4; ++tile) {
            int s = s0 + tile*16 + lr;
            size_t idx = ((size_t)h*S_LEN + s)*HD + d0;
            uint2 pkR, pkI;
            pkR.x = pk_bf16((accR[tile][0]+bR[0])*osc, (accR[tile][1]+bR[1])*osc);
            pkR.y = pk_bf16((accR[tile][2]+bR[2])*osc, (accR[tile][3]+bR[3])*osc);
            pkI.x = pk_bf16((accI[tile][0]+bI[0])*osc, (accI[tile][1]+bI[1])*osc);
            pkI.y = pk_bf16((accI[tile][2]+bI[2])*osc, (accI[tile][3]+bI[3])*osc);
            *(uint2*)&pr[idx] = pkR;
            *(uint2*)&pi[idx] = pkI;
        }
    } else {
        unsigned short* tr = ws + 4 * (size_t)PLANE_U;
        unsigned short* ti = tr + PLANE_U;
        const int sbase = s0 + wave*16 + g*4;    // NATURAL key order
        #pragma unroll
        for (int tile = 0; tile < 4; ++tile) {
            int o = o0 + tile*16 + lr;
            int h = o >> 5, d = o & 31;
            float2 bb = b2[o];
            size_t idx = ((size_t)h*HD + d)*S_LEN + sbase;
            uint2 pkR, pkI;
            pkR.x = pk_bf16(accR[tile][0]+bb.x, accR[tile][1]+bb.x);
            pkR.y = pk_bf16(accR[tile][2]+bb.x, accR[tile][3]+bb.x);
            pkI.x = pk_bf16(accI[tile][0]+bb.y, accI[tile][1]+bb.y);
            pkI.y = pk_bf16(accI[tile][2]+bb.y, accI[tile][3]+bb.y);
            *(uint2*)&tr[idx] = pkR;
            *(uint2*)&ti[idx] = pkI;
        }
    }
}

// ---------------- MFMA flash attention: 32x32x16, split-K 4 --------------
// One 32x32x16 covers all 32 q-rows of the block. QK^T: S = mfma(K, Q) with
// the KEY->A-row permutation kappa(row) chosen so D-reg r of lane-half b
// holds key {8b+r} (r<8) / {16+8b+r-8} (r>=8) -> P packs DIRECTLY into the
// PV B-fragment (8 cvt_pk, no cross-lane, no LDS). PV: O^T = mfma(V^T, P)
// with V^T natural [h][d][s]. |s| only needs sR^2+sI^2, sign of sI free up
// to the in-product negation (transient -Ki, 8 XOR/group). 4 waves/block
// (256 thr) x split-K 4 -> 4 blocks/CU all-resident, no tail. Partials
// purely additive (no max tracking; |s| <= ~15). Combine: two-stage into
// [2][32][33] float2 (conflict-free, l in pad slot 32).
#define RROW 33

__global__ __launch_bounds__(256, 4)
void attn_mfma(const unsigned short* __restrict__ ws, float* __restrict__ out)
{
    const int bid   = blockIdx.x;       // 64 q-blocks x 16 heads
    const int h     = bid & (NH - 1);   // bid%8 = head%8 -> per-XCD KV locality
    const int qblk  = bid >> 4;         // 0..63
    const int wave  = threadIdx.x >> 6; // 0..3 -> k-range owner
    const int l     = threadIdx.x & 63;
    const int q     = l & 31;           // q-col AND V^T d-row AND PV q-col
    const int b     = l >> 5;           // lane half

    const unsigned short* qr  = ws + 0*(size_t)PLANE_U + (size_t)h*S_LEN*HD;
    const unsigned short* qi  = ws + 1*(size_t)PLANE_U + (size_t)h*S_LEN*HD;
    const unsigned short* kr  = ws + 2*(size_t)PLANE_U + (size_t)h*S_LEN*HD;
    const unsigned short* ki  = ws + 3*(size_t)PLANE_U + (size_t)h*S_LEN*HD;
    const unsigned short* vtr = ws + 4*(size_t)PLANE_U + (size_t)h*HD*S_LEN;
    const unsigned short* vti = ws + 5*(size_t)PLANE_U + (size_t)h*HD*S_LEN;

    const int q0 = qblk * 32;

    // key -> A-row permutation (see header comment); fixed per lane
    const int row   = q;
    const int kappa = (row & 16) + (((row >> 2) & 1) << 3) + (row & 3)
                    + (((row >> 3) & 1) << 2);

    // Q fragments (B-operand): lane supplies Q[q][d = b*8+j] (lo) / +16 (hi)
    bf16x8 bQr_lo = *(const bf16x8*)&qr[(size_t)(q0 + q)*HD + b*8];
    bf16x8 bQr_hi = *(const bf16x8*)&qr[(size_t)(q0 + q)*HD + 16 + b*8];
    bf16x8 bQi_lo = *(const bf16x8*)&qi[(size_t)(q0 + q)*HD + b*8];
    bf16x8 bQi_hi = *(const bf16x8*)&qi[(size_t)(q0 + q)*HD + 16 + b*8];

    // LDS only for the end-of-kernel two-stage combine: [2][32][33] float2
    __shared__ __align__(16) float2 red[2*32*RROW];

    f32x16 accR, accI;
    #pragma unroll
    for (int r = 0; r < 16; ++r) { accR[r] = 0.f; accI[r] = 0.f; }
    float lsum = 0.f;

    const f32x16 z16 = {0,0,0,0,0,0,0,0,0,0,0,0,0,0,0,0};
    const int kbeg = wave * 512;
    for (int k0 = kbeg; k0 < kbeg + 512; k0 += 32) {
        // ---- K fragments: A[row][k] with permuted key rows ----
        const size_t krow = (size_t)(k0 + kappa)*HD + b*8;
        bf16x8 aKr_lo = *(const bf16x8*)&kr[krow];
        bf16x8 aKr_hi = *(const bf16x8*)&kr[krow + 16];
        bf16x8 aKi_lo = *(const bf16x8*)&ki[krow];
        bf16x8 aKi_hi = *(const bf16x8*)&ki[krow + 16];
        bf16x8 aKin_lo, aKin_hi;    // -Ki (transient)
        #pragma unroll
        for (int j = 0; j < 4; ++j) {
            ((unsigned int*)&aKin_lo)[j] = ((const unsigned int*)&aKi_lo)[j] ^ 0x80008000u;
            ((unsigned int*)&aKin_hi)[j] = ((const unsigned int*)&aKi_hi)[j] ^ 0x80008000u;
        }
        // ---- QK^T: 8 mfma, two independent 4-chains ----
        f32x16 sR = __builtin_amdgcn_mfma_f32_32x32x16_bf16(aKr_lo,  bQr_lo, z16, 0, 0, 0);
        f32x16 sI = __builtin_amdgcn_mfma_f32_32x32x16_bf16(aKin_lo, bQr_lo, z16, 0, 0, 0);
        sR = __builtin_amdgcn_mfma_f32_32x32x16_bf16(aKr_hi,  bQr_hi, sR, 0, 0, 0);
        sI = __builtin_amdgcn_mfma_f32_32x32x16_bf16(aKin_hi, bQr_hi, sI, 0, 0, 0);
        sR = __builtin_amdgcn_mfma_f32_32x32x16_bf16(aKi_lo,  bQi_lo, sR, 0, 0, 0);
        sI = __builtin_amdgcn_mfma_f32_32x32x16_bf16(aKr_lo,  bQi_lo, sI, 0, 0, 0);
        sR = __builtin_amdgcn_mfma_f32_32x32x16_bf16(aKi_hi,  bQi_hi, sR, 0, 0, 0);
        sI = __builtin_amdgcn_mfma_f32_32x32x16_bf16(aKr_hi,  bQi_hi, sI, 0, 0, 0);
        // ---- softmax: p[r] lands exactly in PV B-frag order ----
        bf16x8 bP1, bP2;
        unsigned int* p1 = (unsigned int*)&bP1;
        unsigned int* p2 = (unsigned int*)&bP2;
        #pragma unroll
        for (int r2 = 0; r2 < 8; ++r2) {
            int r = 2*r2;
            float v0 = __expf(__builtin_amdgcn_sqrtf(fmaf(sR[r],   sR[r],   sI[r]*sI[r])));
            float v1 = __expf(__builtin_amdgcn_sqrtf(fmaf(sR[r+1], sR[r+1], sI[r+1]*sI[r+1])));
            lsum += v0 + v1;
            if (r2 < 4) p1[r2]     = pk_bf16(v0, v1);
            else        p2[r2 - 4] = pk_bf16(v0, v1);
        }
        // ---- PV: A = V^T (natural, 16B loads), B = P in-register ----
        const size_t vrow = (size_t)q*S_LEN + k0 + b*8;
        bf16x8 aVr_lo = *(const bf16x8*)&vtr[vrow];
        bf16x8 aVr_hi = *(const bf16x8*)&vtr[vrow + 16];
        bf16x8 aVi_lo = *(const bf16x8*)&vti[vrow];
        bf16x8 aVi_hi = *(const bf16x8*)&vti[vrow + 16];
        accR = __builtin_amdgcn_mfma_f32_32x32x16_bf16(aVr_lo, bP1, accR, 0, 0, 0);
        accI = __builtin_amdgcn_mfma_f32_32x32x16_bf16(aVi_lo, bP1, accI, 0, 0, 0);
        accR = __builtin_amdgcn_mfma_f32_32x32x16_bf16(aVr_hi, bP2, accR, 0, 0, 0);
        accI = __builtin_amdgcn_mfma_f32_32x32x16_bf16(aVi_hi, bP2, accI, 0, 0, 0);
    }

    // lane pair (l, l^32) handled complementary key halves of the same q
    lsum += __shfl_xor(lsum, 32);

    // ---- two-stage combine: waves 0,1 write; 2,3 add; all reduce ----
    const int rrow = ((wave & 1) * 32 + q) * RROW;
    __syncthreads();
    if (wave < 2) {
        #pragma unroll
        for (int r = 0; r < 16; ++r) {
            int d = (r & 3) + 8*(r >> 2) + 4*b;   // PV D row = output d
            red[rrow + d] = make_float2(accR[r], accI[r]);
        }
        if (b == 0) red[rrow + 32].x = lsum;
    }
    __syncthreads();
    if (wave >= 2) {
        #pragma unroll
        for (int r = 0; r < 16; ++r) {
            int d = (r & 3) + 8*(r >> 2) + 4*b;
            float2 v = red[rrow + d];
            v.x += accR[r]; v.y += accI[r];
            red[rrow + d] = v;
        }
        if (b == 0) red[rrow + 32].x += lsum;
    }
    __syncthreads();

    // thread i: q-row = i>>3, d = (i&7)*4 .. +3 ; sum 2 stage-partials
    {
        const int i  = threadIdx.x;
        const int oq = i >> 3;
        const int d0 = (i & 7) * 4;
        float sl = red[oq*RROW + 32].x + red[(32 + oq)*RROW + 32].x;
        float inv = 1.0f / sl;
        float2* o2 = (float2*)out;
        #pragma unroll
        for (int dd = 0; dd < 4; ++dd) {
            int d = d0 + dd;
            float2 v0 = red[oq*RROW + d];
            float2 v1 = red[(32 + oq)*RROW + d];
            o2[(size_t)(q0 + oq)*C_DIM + h*HD + d] =
                make_float2((v0.x + v1.x)*inv, (v0.y + v1.y)*inv);
        }
    }
}

extern "C" void kernel_launch(void* const* d_in, const int* in_sizes, int n_in,
                              void* d_out, int out_size, void* d_ws, size_t ws_size,
                              hipStream_t stream)
{
    const float* Q  = (const float*)d_in[0];
    const float* V  = (const float*)d_in[1];
    const float* K  = (const float*)d_in[2];
    const float* Wq = (const float*)d_in[3];
    const float* bq = (const float*)d_in[4];
    const float* Wk = (const float*)d_in[5];
    const float* bk = (const float*)d_in[6];
    const float* Wv = (const float*)d_in[7];
    const float* bv = (const float*)d_in[8];
    unsigned short* ws = (unsigned short*)d_ws;   // 6 planes * 2MB = 12MB
    float* out = (float*)d_out;

    dim3 gp(S_LEN/64, C_DIM/64, 3);
    proj_mfma<<<gp, 256, 0, stream>>>(Q, V, K, Wq, bq, Wk, bk, Wv, bv, ws);

    attn_mfma<<<dim3(64*NH), 256, 0, stream>>>(ws, out);
}